// Round 4
// baseline (4703.869 us; speedup 1.0000x reference)
//
#include <hip/hip_runtime.h>

#define BD 256   // batch
#define HD 1024  // hidden
#define LATD 512 // latent
#define OD 128   // output dim
#define TS 100   // seq_len (fixed by problem)

typedef __attribute__((ext_vector_type(8))) short s16x8;
typedef __attribute__((ext_vector_type(4))) short s16x4;
typedef __attribute__((ext_vector_type(4))) float f32x4;

__device__ __forceinline__ float b2f(short s) {
  return __uint_as_float(((unsigned)(unsigned short)s) << 16);
}
__device__ __forceinline__ short f2b(float f) {
  unsigned u = __float_as_uint(f);
  u += 0x7fff + ((u >> 16) & 1);  // round-to-nearest-even
  return (short)(u >> 16);
}
__device__ __forceinline__ float sigm(float x) { return 1.f / (1.f + __expf(-x)); }
// saturates cleanly (x->+inf -> 1, x->-inf -> -1), no NaN for finite x
__device__ __forceinline__ float tanh_f(float x) { return 1.f - 2.f / (__expf(2.f * x) + 1.f); }

// ---------------- conversion / small one-time kernels (fp32 inputs) ----------------

__global__ __launch_bounds__(256) void cvt_k(const float* __restrict__ in,
                                             short* __restrict__ out) {
  int i = (blockIdx.x * 256 + threadIdx.x) * 4;
  f32x4 v = *(const f32x4*)(in + i);
  s16x4 o;
#pragma unroll
  for (int e = 0; e < 4; ++e) o[e] = f2b(v[e]);
  *(s16x4*)(out + i) = o;
}

__global__ __launch_bounds__(256) void bsum_k(const float* __restrict__ bi,
                                              const float* __restrict__ bh,
                                              float* __restrict__ bs) {
  int i = blockIdx.x * 256 + threadIdx.x;
  bs[i] = bi[i] + bh[i];
}

// xrow = relu(start_token @ emb_fc_w^T + emb_fc_b), one row [HD], stored bf16
__global__ __launch_bounds__(256) void x0_k(const float* __restrict__ st,
                                            const float* __restrict__ W,
                                            const float* __restrict__ bias,
                                            short* __restrict__ xrow) {
  int j = blockIdx.x * 256 + threadIdx.x;  // < HD
  float acc = 0.f;
  for (int k = 0; k < OD; ++k) acc += st[k] * W[j * OD + k];
  acc += bias[j];
  xrow[j] = f2b(acc > 0.f ? acc : 0.f);
}

__global__ __launch_bounds__(256) void bcast_k(const short* __restrict__ xrow,
                                               short* __restrict__ xb) {
  int i = blockIdx.x * 256 + threadIdx.x;
  xb[i] = xrow[i & (HD - 1)];
}

// out = leaky_relu(in @ W^T + b), N = 1024 outputs per row. fp32 in/weights.
template <bool OUT_BF16>
__global__ __launch_bounds__(256) void fc_lrelu(const float* __restrict__ in_,
                                                const float* __restrict__ W,
                                                const float* __restrict__ bias,
                                                void* __restrict__ out_, int K) {
  int idx = blockIdx.x * 256 + threadIdx.x;
  int m = idx >> 10, n = idx & 1023;
  const float* Wr = W + n * K;
  const float* in = in_ + m * K;
  float acc = 0.f;
  for (int k = 0; k < K; k += 4) {
    f32x4 wv = *(const f32x4*)(Wr + k);
    f32x4 iv = *(const f32x4*)(in + k);
#pragma unroll
    for (int e = 0; e < 4; ++e) acc += iv[e] * wv[e];
  }
  acc += bias[n];
  float v = acc > 0.f ? acc : 0.01f * acc;
  if (OUT_BF16)
    ((short*)out_)[idx] = f2b(v);
  else
    ((float*)out_)[idx] = v;
}

__global__ __launch_bounds__(256) void num_k(const float* __restrict__ n1,
                                             const float* __restrict__ w,
                                             const float* __restrict__ bias,
                                             float* __restrict__ out) {
  int m = threadIdx.x;
  const float* r = n1 + m * HD;
  float acc = 0.f;
  for (int k = 0; k < HD; ++k) acc += r[k] * w[k];
  acc += bias[0];
  out[m] = acc > 0.f ? acc : 0.f;
}

__global__ __launch_bounds__(256) void mass_k(const float* __restrict__ m2,
                                              const float* __restrict__ w,
                                              const float* __restrict__ bias,
                                              float* __restrict__ out) {
  int m = threadIdx.x;
  const float* r = m2 + m * HD;
  float z0 = 0.f, z1 = 0.f;
  for (int k = 0; k < HD; ++k) {
    float v = r[k];
    z0 += v * w[k];
    z1 += v * w[HD + k];
  }
  z0 += bias[0];
  z1 += bias[1];
  float mx = fmaxf(z0, z1);
  float e0 = __expf(z0 - mx), e1 = __expf(z1 - mx);
  float s = e0 + e1;
  out[m * 2] = e0 / s;
  out[m * 2 + 1] = e1 / s;
}

__global__ __launch_bounds__(256) void copy_h_k(const short* __restrict__ h,
                                                float* __restrict__ out) {
  int i = blockIdx.x * 256 + threadIdx.x;
  out[i] = b2f(h[i]);
}
__global__ __launch_bounds__(256) void copy_c_k(const float* __restrict__ c,
                                                float* __restrict__ out) {
  int i = blockIdx.x * 256 + threadIdx.x;
  out[i] = c[i];
}

// ---------------- fused LSTM step (bf16 MFMA, fp32 cell state) ----------------
// gates[m, g*HD+col] = sum_k xb[m,k] Wih[g*HD+col,k] + hb[m,k] Whh[g*HD+col,k] (+bsum)
// Block tile: M=64 (blockIdx.y), 32 h-cols (blockIdx.x) -> 128 gate rows (4 gates).
// LDS chunk-major: 16B chunk(row,kc) at chunk idx (row/16)*64 + kc*16 + row%16.
__global__ __launch_bounds__(256) void lstm_step(
    const short* __restrict__ xb, const short* __restrict__ hb,
    float* __restrict__ cbuf, const short* __restrict__ Wih,
    const short* __restrict__ Whh, const float* __restrict__ bsum,
    short* __restrict__ xb_out, short* __restrict__ hb_out,
    short* __restrict__ hs_out) {
  __shared__ __align__(16) short sA[2][64 * 32];   // [xb, hb]
  __shared__ __align__(16) short sB[2][128 * 32];  // [Wih, Whh]

  const int tid = threadIdx.x;
  const int l = tid & 63;
  const int wm = (tid >> 6) & 1, wn = tid >> 7;
  const int quad = l >> 4, lan = l & 15;
  const int c0 = blockIdx.x * 32;
  const int m0 = blockIdx.y * 64;

  const int a_row = ((tid >> 6) << 4) | (tid & 15);
  const int a_kc = (tid >> 4) & 3;
  const int b_rr0 = a_row;                     // 0..63
  const int b_rr1 = a_row + 64;                // 64..127
  const int b_n0 = ((b_rr0 >> 5) << 10) + c0 + (b_rr0 & 31);
  const int b_n1 = ((b_rr1 >> 5) << 10) + c0 + (b_rr1 & 31);

  f32x4 acc[2][4] = {};

  for (int k0 = 0; k0 < HD; k0 += 32) {
    const int ka = k0 + a_kc * 8;
    s16x8 vx = *(const s16x8*)(xb + (m0 + a_row) * HD + ka);
    s16x8 vh = *(const s16x8*)(hb + (m0 + a_row) * HD + ka);
    s16x8 wi0 = *(const s16x8*)(Wih + b_n0 * HD + ka);
    s16x8 wh0 = *(const s16x8*)(Whh + b_n0 * HD + ka);
    s16x8 wi1 = *(const s16x8*)(Wih + b_n1 * HD + ka);
    s16x8 wh1 = *(const s16x8*)(Whh + b_n1 * HD + ka);
    *(s16x8*)&sA[0][tid * 8] = vx;
    *(s16x8*)&sA[1][tid * 8] = vh;
    *(s16x8*)&sB[0][tid * 8] = wi0;
    *(s16x8*)&sB[1][tid * 8] = wh0;
    *(s16x8*)&sB[0][(tid + 256) * 8] = wi1;
    *(s16x8*)&sB[1][(tid + 256) * 8] = wh1;
    __syncthreads();

    s16x8 ax[2], ah[2], bi[4], bh[4];
#pragma unroll
    for (int mt = 0; mt < 2; ++mt) {
      int ci = (wm * 2 + mt) * 64 + quad * 16 + lan;
      ax[mt] = *(const s16x8*)&sA[0][ci * 8];
      ah[mt] = *(const s16x8*)&sA[1][ci * 8];
    }
#pragma unroll
    for (int g = 0; g < 4; ++g) {
      int ci = (g * 2 + wn) * 64 + quad * 16 + lan;
      bi[g] = *(const s16x8*)&sB[0][ci * 8];
      bh[g] = *(const s16x8*)&sB[1][ci * 8];
    }
#pragma unroll
    for (int mt = 0; mt < 2; ++mt)
#pragma unroll
      for (int g = 0; g < 4; ++g) {
        acc[mt][g] = __builtin_amdgcn_mfma_f32_16x16x32_bf16(ax[mt], bi[g], acc[mt][g], 0, 0, 0);
        acc[mt][g] = __builtin_amdgcn_mfma_f32_16x16x32_bf16(ah[mt], bh[g], acc[mt][g], 0, 0, 0);
      }
    __syncthreads();
  }

  // epilogue: C/D layout row = quad*4 + j, col = lan  [measured m89/m91]
  const int colh = c0 + wn * 16 + lan;
  const float bsi = bsum[colh];
  const float bsf = bsum[HD + colh];
  const float bsg = bsum[2 * HD + colh];
  const float bso = bsum[3 * HD + colh];
#pragma unroll
  for (int mt = 0; mt < 2; ++mt)
#pragma unroll
    for (int j = 0; j < 4; ++j) {
      int m = m0 + (wm * 2 + mt) * 16 + quad * 4 + j;
      float gi = acc[mt][0][j] + bsi;
      float gf = acc[mt][1][j] + bsf;
      float gg = acc[mt][2][j] + bsg;
      float go = acc[mt][3][j] + bso;
      int idx = m * HD + colh;
      float cn = sigm(gf) * cbuf[idx] + sigm(gi) * tanh_f(gg);
      cbuf[idx] = cn;
      float h = sigm(go) * tanh_f(cn);
      short h16 = f2b(h);
      hb_out[idx] = h16;
      xb_out[idx] = f2b(h > 0.f ? h : 0.f);
      hs_out[idx] = h16;
    }
}

// ---------------- output projection over a CH-step chunk ----------------
__global__ __launch_bounds__(256) void out_proj(const short* __restrict__ hsC,
                                                const short* __restrict__ Wo,
                                                const float* __restrict__ bo,
                                                float* __restrict__ dout, int t0) {
  __shared__ __align__(16) short sA[64 * 32];
  __shared__ __align__(16) short sB[128 * 32];
  const int tid = threadIdx.x;
  const int l = tid & 63, w = tid >> 6;
  const int quad = l >> 4, lan = l & 15;
  const int m0 = blockIdx.x * 64;
  const int a_row = ((tid >> 6) << 4) | (tid & 15);
  const int a_kc = (tid >> 4) & 3;
  const int b_rr1 = a_row + 64;

  f32x4 acc[8] = {};
  for (int k0 = 0; k0 < HD; k0 += 32) {
    const int ka = k0 + a_kc * 8;
    s16x8 va = *(const s16x8*)(hsC + (size_t)(m0 + a_row) * HD + ka);
    s16x8 wb0 = *(const s16x8*)(Wo + a_row * HD + ka);
    s16x8 wb1 = *(const s16x8*)(Wo + b_rr1 * HD + ka);
    *(s16x8*)&sA[tid * 8] = va;
    *(s16x8*)&sB[tid * 8] = wb0;
    *(s16x8*)&sB[(tid + 256) * 8] = wb1;
    __syncthreads();
    s16x8 av = *(const s16x8*)&sA[(w * 64 + quad * 16 + lan) * 8];
#pragma unroll
    for (int nt = 0; nt < 8; ++nt) {
      s16x8 bv = *(const s16x8*)&sB[(nt * 64 + quad * 16 + lan) * 8];
      acc[nt] = __builtin_amdgcn_mfma_f32_16x16x32_bf16(av, bv, acc[nt], 0, 0, 0);
    }
    __syncthreads();
  }
#pragma unroll
  for (int nt = 0; nt < 8; ++nt) {
    int col = nt * 16 + lan;
    float bb = bo[col];
#pragma unroll
    for (int j = 0; j < 4; ++j) {
      int m = m0 + w * 16 + quad * 4 + j;  // chunk-local flat row = tc*BD + b
      int tc = m >> 8, b = m & 255;
      dout[(size_t)(b * TS + t0 + tc) * OD + col] = acc[nt][j] + bb;
    }
  }
}

extern "C" void kernel_launch(void* const* d_in, const int* in_sizes, int n_in,
                              void* d_out, int out_size, void* d_ws, size_t ws_size,
                              hipStream_t stream) {
  // Guard: verify the assumed input ordering/shapes. If violated, do nothing
  // (output stays 0 -> absmax exactly 0.28125, a distinct diagnostic signature).
  static const int exp_sizes[26] = {
      131072, 131072, 128, 524288, 1024, 524288, 1024, 131072, 1024,
      4194304, 4194304, 4096, 4096, 131072, 128, 524288, 1024, 1024, 1,
      524288, 1024, 1048576, 1024, 2048, 2, 1};
  if (n_in < 26) return;
  for (int i = 0; i < 26; ++i)
    if (in_sizes[i] != exp_sizes[i]) return;

  const float* enc_out = (const float*)d_in[0];
  const float* enc_hid = (const float*)d_in[1];
  const float* start_tok = (const float*)d_in[2];
  const float* l2h_w = (const float*)d_in[3];
  const float* l2h_b = (const float*)d_in[4];
  const float* l2h2_w = (const float*)d_in[5];
  const float* l2h2_b = (const float*)d_in[6];
  const float* emb_w = (const float*)d_in[7];
  const float* emb_b = (const float*)d_in[8];
  const float* Wih_f = (const float*)d_in[9];
  const float* Whh_f = (const float*)d_in[10];
  const float* bih = (const float*)d_in[11];
  const float* bhh = (const float*)d_in[12];
  const float* outw_f = (const float*)d_in[13];
  const float* outb = (const float*)d_in[14];
  const float* seq_w = (const float*)d_in[15];
  const float* seq_b = (const float*)d_in[16];
  const float* seq2_w = (const float*)d_in[17];
  const float* seq2_b = (const float*)d_in[18];
  const float* mass_w = (const float*)d_in[19];
  const float* mass_b = (const float*)d_in[20];
  const float* mass2_w = (const float*)d_in[21];
  const float* mass2_b = (const float*)d_in[22];
  const float* mass3_w = (const float*)d_in[23];
  const float* mass3_b = (const float*)d_in[24];
  // d_in[25] = seq_len (int scalar); fixed at 100.

  // ---- workspace layout (16B aligned) ----
  char* p = (char*)d_ws;
  float* c_buf = (float*)p;   p += (size_t)BD * HD * 4;      // 1 MB
  float* bsum = (float*)p;    p += (size_t)4 * HD * 4;       // 16 KB
  float* n1 = (float*)p;      p += (size_t)BD * HD * 4;      // 1 MB
  float* m1 = (float*)p;      p += (size_t)BD * HD * 4;      // 1 MB
  float* m2 = (float*)p;      p += (size_t)BD * HD * 4;      // 1 MB
  short* xrow = (short*)p;    p += (size_t)HD * 2;           // 2 KB
  short* xbA = (short*)p;     p += (size_t)BD * HD * 2;
  short* hbA = (short*)p;     p += (size_t)BD * HD * 2;
  short* xbB = (short*)p;     p += (size_t)BD * HD * 2;
  short* hbB = (short*)p;     p += (size_t)BD * HD * 2;      // +2 MB
  short* Wih = (short*)p;     p += (size_t)4 * HD * HD * 2;  // 8 MB
  short* Whh = (short*)p;     p += (size_t)4 * HD * HD * 2;  // 8 MB
  short* outw = (short*)p;    p += (size_t)OD * HD * 2;      // 256 KB
  short* hsC = (short*)p;     // CH * BD * HD bf16
  size_t fixed_bytes = (size_t)(p - (char*)d_ws);
  const size_t step_bytes = (size_t)BD * HD * 2;
  int CH = 0;
  const int cands[7] = {25, 20, 10, 5, 4, 2, 1};
  for (int ci = 0; ci < 7; ++ci) {
    if (fixed_bytes + (size_t)cands[ci] * step_bytes <= ws_size) { CH = cands[ci]; break; }
  }
  if (CH == 0) return;  // workspace too small: bail (diagnostic signature)

  float* dout = (float*)d_out;
  float* o_dec = dout;                                // [B][TS][OD]
  float* o_h = dout + (size_t)BD * TS * OD;           // [1][B][HD]
  float* o_c = o_h + (size_t)BD * HD;                 // [1][B][HD]
  float* o_num = o_c + (size_t)BD * HD;               // [B][1]
  float* o_mass = o_num + BD;                         // [B][2]

  // weight conversions fp32 -> bf16
  cvt_k<<<4 * HD * HD / 1024, 256, 0, stream>>>(Wih_f, Wih);
  cvt_k<<<4 * HD * HD / 1024, 256, 0, stream>>>(Whh_f, Whh);
  cvt_k<<<OD * HD / 1024, 256, 0, stream>>>(outw_f, outw);

  bsum_k<<<16, 256, 0, stream>>>(bih, bhh, bsum);
  x0_k<<<4, 256, 0, stream>>>(start_tok, emb_w, emb_b, xrow);
  bcast_k<<<BD * HD / 256, 256, 0, stream>>>(xrow, xbA);
  fc_lrelu<true><<<BD * HD / 256, 256, 0, stream>>>(enc_hid, l2h_w, l2h_b, hbA, LATD);
  fc_lrelu<false><<<BD * HD / 256, 256, 0, stream>>>(enc_hid, l2h2_w, l2h2_b, c_buf, LATD);
  fc_lrelu<false><<<BD * HD / 256, 256, 0, stream>>>(enc_out, seq_w, seq_b, n1, LATD);
  fc_lrelu<false><<<BD * HD / 256, 256, 0, stream>>>(enc_out, mass_w, mass_b, m1, LATD);
  fc_lrelu<false><<<BD * HD / 256, 256, 0, stream>>>(m1, mass2_w, mass2_b, m2, HD);
  num_k<<<1, 256, 0, stream>>>(n1, seq2_w, seq2_b, o_num);
  mass_k<<<1, 256, 0, stream>>>(m2, mass3_w, mass3_b, o_mass);

  short* xs[2] = {xbA, xbB};
  short* hh[2] = {hbA, hbB};
  for (int t = 0; t < TS; ++t) {
    int i = t & 1;
    lstm_step<<<dim3(32, 4), 256, 0, stream>>>(xs[i], hh[i], c_buf, Wih, Whh, bsum,
                                               xs[1 - i], hh[1 - i],
                                               hsC + (size_t)(t % CH) * BD * HD);
    if ((t + 1) % CH == 0) {
      out_proj<<<CH * BD / 64, 256, 0, stream>>>(hsC, outw, outb, o_dec, t + 1 - CH);
    }
  }
  // TS even -> final h lives in hbA, final c in c_buf
  copy_h_k<<<BD * HD / 256, 256, 0, stream>>>(hbA, o_h);
  copy_c_k<<<BD * HD / 256, 256, 0, stream>>>(c_buf, o_c);
}

// Round 5
// 4620.040 us; speedup vs baseline: 1.0181x; 1.0181x over previous
//
#include <hip/hip_runtime.h>

#define BD 256   // batch
#define HD 1024  // hidden
#define KC 2048  // concatenated K = [x | h]
#define LATD 512 // latent
#define OD 128   // output dim
#define TS 100   // seq_len (fixed by problem)

typedef __attribute__((ext_vector_type(8))) short s16x8;
typedef __attribute__((ext_vector_type(4))) float f32x4;

__device__ __forceinline__ float b2f(short s) {
  return __uint_as_float(((unsigned)(unsigned short)s) << 16);
}
__device__ __forceinline__ short f2b(float f) {
  unsigned u = __float_as_uint(f);
  u += 0x7fff + ((u >> 16) & 1);  // RNE
  return (short)(u >> 16);
}
__device__ __forceinline__ float sigm(float x) { return 1.f / (1.f + __expf(-x)); }
__device__ __forceinline__ float tanh_f(float x) { return 1.f - 2.f / (__expf(2.f * x) + 1.f); }

// ---------------- one-time prep kernels ----------------

// fp32 -> bf16, 8 elems/thread
__global__ __launch_bounds__(256) void cvt8_k(const float* __restrict__ in,
                                              short* __restrict__ out) {
  int i = (blockIdx.x * 256 + threadIdx.x) * 8;
  f32x4 a = *(const f32x4*)(in + i), b = *(const f32x4*)(in + i + 4);
  s16x8 o;
#pragma unroll
  for (int e = 0; e < 4; ++e) { o[e] = f2b(a[e]); o[4 + e] = f2b(b[e]); }
  *(s16x8*)(out + i) = o;
}

// Wcat[n][k] = (k<1024 ? Wih[n][k] : Whh[n][k-1024]) as bf16
__global__ __launch_bounds__(256) void wcat_k(const float* __restrict__ Wih,
                                              const float* __restrict__ Whh,
                                              short* __restrict__ Wcat) {
  int i = (blockIdx.x * 256 + threadIdx.x) * 8;  // over 4096*2048
  int n = i >> 11, k = i & 2047;
  const float* src = (k < HD) ? (Wih + n * HD + k) : (Whh + n * HD + (k - HD));
  f32x4 a = *(const f32x4*)src, b = *(const f32x4*)(src + 4);
  s16x8 o;
#pragma unroll
  for (int e = 0; e < 4; ++e) { o[e] = f2b(a[e]); o[4 + e] = f2b(b[e]); }
  *(s16x8*)(Wcat + i) = o;
}

__global__ __launch_bounds__(256) void bsum_k(const float* __restrict__ bi,
                                              const float* __restrict__ bh,
                                              float* __restrict__ bs) {
  int i = blockIdx.x * 256 + threadIdx.x;
  bs[i] = bi[i] + bh[i];
}

// xrow = relu(start_token @ emb_fc_w^T + emb_fc_b), one row [HD], bf16
__global__ __launch_bounds__(256) void x0_k(const float* __restrict__ st,
                                            const float* __restrict__ W,
                                            const float* __restrict__ bias,
                                            short* __restrict__ xrow) {
  int j = blockIdx.x * 256 + threadIdx.x;
  float acc = 0.f;
  for (int k = 0; k < OD; ++k) acc += st[k] * W[j * OD + k];
  acc += bias[j];
  xrow[j] = f2b(acc > 0.f ? acc : 0.f);
}

// xh[m][c] = xrow[c] (x-half init)
__global__ __launch_bounds__(256) void bcast_k(const short* __restrict__ xrow,
                                               short* __restrict__ xh) {
  int i = blockIdx.x * 256 + threadIdx.x;  // over BD*HD
  int m = i >> 10, c = i & 1023;
  xh[m * KC + c] = xrow[c];
}

// ---------------- head GEMM: out = lrelu(A @ W^T + b), N=1024, M=256 ----------------
// LDS-free MFMA; A fp32 or bf16 (inline cvt); W fp32 (inline cvt).
// grid (16 nb, 4 mb), 256 thr. Wave: 16m x 64n (4 n-frags).
template <int K, bool IN_BF16, bool OUT_F32>
__global__ __launch_bounds__(256) void fc_mfma(const void* __restrict__ in_,
                                               const float* __restrict__ W,
                                               const float* __restrict__ bias,
                                               void* __restrict__ out_,
                                               int ostride, int ooff) {
  const int tid = threadIdx.x;
  const int w = tid >> 6, lan = tid & 15, quad = (tid & 63) >> 4;
  const int n0 = blockIdx.x * 64;
  const int m0 = blockIdx.y * 64;
  const int arow = m0 + w * 16 + lan;
  f32x4 acc[4] = {};
  for (int k0 = 0; k0 < K; k0 += 32) {
    const int ka = k0 + quad * 8;
    s16x8 af;
    if (IN_BF16) {
      af = *(const s16x8*)((const short*)in_ + arow * K + ka);
    } else {
      const float* ap = (const float*)in_ + arow * K + ka;
      f32x4 a0 = *(const f32x4*)ap, a1 = *(const f32x4*)(ap + 4);
#pragma unroll
      for (int e = 0; e < 4; ++e) { af[e] = f2b(a0[e]); af[4 + e] = f2b(a1[e]); }
    }
#pragma unroll
    for (int nf = 0; nf < 4; ++nf) {
      const float* bp = W + (n0 + nf * 16 + lan) * K + ka;
      f32x4 b0 = *(const f32x4*)bp, b1 = *(const f32x4*)(bp + 4);
      s16x8 bf;
#pragma unroll
      for (int e = 0; e < 4; ++e) { bf[e] = f2b(b0[e]); bf[4 + e] = f2b(b1[e]); }
      acc[nf] = __builtin_amdgcn_mfma_f32_16x16x32_bf16(af, bf, acc[nf], 0, 0, 0);
    }
  }
#pragma unroll
  for (int nf = 0; nf < 4; ++nf) {
    int col = n0 + nf * 16 + lan;
    float bb = bias[col];
#pragma unroll
    for (int j = 0; j < 4; ++j) {
      int m = m0 + w * 16 + quad * 4 + j;
      float v = acc[nf][j] + bb;
      v = v > 0.f ? v : 0.01f * v;
      if (OUT_F32)
        ((float*)out_)[m * 1024 + col] = v;
      else
        ((short*)out_)[m * ostride + ooff + col] = f2b(v);
    }
  }
}

// num = relu(n1 @ seq2_w^T + b): one wave per batch row
__global__ __launch_bounds__(256) void num_k(const float* __restrict__ n1,
                                             const float* __restrict__ w2,
                                             const float* __restrict__ b2,
                                             float* __restrict__ out) {
  int l = threadIdx.x & 63, w = threadIdx.x >> 6;
  int m = blockIdx.x * 4 + w;
  const float* r = n1 + m * HD + l * 16;
  const float* wv = w2 + l * 16;
  float acc = 0.f;
#pragma unroll
  for (int c = 0; c < 4; ++c) {
    f32x4 a = *(const f32x4*)(r + c * 4), b = *(const f32x4*)(wv + c * 4);
#pragma unroll
    for (int e = 0; e < 4; ++e) acc += a[e] * b[e];
  }
  for (int off = 32; off; off >>= 1) acc += __shfl_down(acc, off);
  if (l == 0) {
    float v = acc + b2[0];
    out[m] = v > 0.f ? v : 0.f;
  }
}

// mass = softmax(m2 @ mass3_w^T + b): one wave per batch row, 2 outputs
__global__ __launch_bounds__(256) void mass_k(const short* __restrict__ m2,
                                              const float* __restrict__ w3,
                                              const float* __restrict__ b3,
                                              float* __restrict__ out) {
  int l = threadIdx.x & 63, w = threadIdx.x >> 6;
  int m = blockIdx.x * 4 + w;
  const short* r = m2 + m * HD + l * 16;
  s16x8 v0 = *(const s16x8*)r, v1 = *(const s16x8*)(r + 8);
  float z0 = 0.f, z1 = 0.f;
#pragma unroll
  for (int e = 0; e < 8; ++e) {
    float a = b2f(v0[e]), b = b2f(v1[e]);
    z0 += a * w3[l * 16 + e] + b * w3[l * 16 + 8 + e];
    z1 += a * w3[HD + l * 16 + e] + b * w3[HD + l * 16 + 8 + e];
  }
  for (int off = 32; off; off >>= 1) {
    z0 += __shfl_down(z0, off);
    z1 += __shfl_down(z1, off);
  }
  if (l == 0) {
    z0 += b3[0]; z1 += b3[1];
    float mx = fmaxf(z0, z1);
    float e0 = __expf(z0 - mx), e1 = __expf(z1 - mx);
    float s = e0 + e1;
    out[m * 2] = e0 / s;
    out[m * 2 + 1] = e1 / s;
  }
}

__global__ __launch_bounds__(256) void copy_h_k(const short* __restrict__ xh,
                                                float* __restrict__ out) {
  int i = blockIdx.x * 256 + threadIdx.x;  // over BD*HD
  int m = i >> 10, c = i & 1023;
  out[i] = b2f(xh[m * KC + HD + c]);
}
__global__ __launch_bounds__(256) void copy_c_k(const float* __restrict__ c,
                                                float* __restrict__ out) {
  int i = blockIdx.x * 256 + threadIdx.x;
  out[i] = c[i];
}

// ---------------- fused LSTM step: LDS-free MFMA ----------------
// gates[m, g*HD+ch] = sum_k xh[m,k] * Wcat[g*HD+ch, k]  (+bsum in epilogue)
// grid (64, 4): bx -> 16 h-cols, by -> 64 m-rows. 4 waves split m.
// Wave: 16m x (16 h-cols x 4 gates). Fragments loaded direct global->VGPR
// (lane->row, quad->k-chunk; layout HW-verified by the round-4 pass).
__global__ __launch_bounds__(256) void lstm_step(
    const short* __restrict__ xh, float* __restrict__ cbuf,
    const short* __restrict__ Wcat, const float* __restrict__ bsum,
    short* __restrict__ xh_out, short* __restrict__ hs_out) {
  const int tid = threadIdx.x;
  const int w = tid >> 6, lan = tid & 15, quad = (tid & 63) >> 4;
  const int c0 = blockIdx.x * 16;
  const int m0 = blockIdx.y * 64;
  const int arow = m0 + w * 16 + lan;
  const short* ap = xh + arow * KC;
  const short* bp0 = Wcat + (size_t)(0 * HD + c0 + lan) * KC;
  const short* bp1 = Wcat + (size_t)(1 * HD + c0 + lan) * KC;
  const short* bp2 = Wcat + (size_t)(2 * HD + c0 + lan) * KC;
  const short* bp3 = Wcat + (size_t)(3 * HD + c0 + lan) * KC;

  f32x4 acc0 = {}, acc1 = {}, acc2 = {}, acc3 = {};
#pragma unroll 4
  for (int k0 = 0; k0 < KC; k0 += 32) {
    const int ka = k0 + quad * 8;
    s16x8 a = *(const s16x8*)(ap + ka);
    s16x8 b0 = *(const s16x8*)(bp0 + ka);
    s16x8 b1 = *(const s16x8*)(bp1 + ka);
    s16x8 b2 = *(const s16x8*)(bp2 + ka);
    s16x8 b3 = *(const s16x8*)(bp3 + ka);
    acc0 = __builtin_amdgcn_mfma_f32_16x16x32_bf16(a, b0, acc0, 0, 0, 0);
    acc1 = __builtin_amdgcn_mfma_f32_16x16x32_bf16(a, b1, acc1, 0, 0, 0);
    acc2 = __builtin_amdgcn_mfma_f32_16x16x32_bf16(a, b2, acc2, 0, 0, 0);
    acc3 = __builtin_amdgcn_mfma_f32_16x16x32_bf16(a, b3, acc3, 0, 0, 0);
  }

  const int ch = c0 + lan;
  const float bsi = bsum[ch];
  const float bsf = bsum[HD + ch];
  const float bsg = bsum[2 * HD + ch];
  const float bso = bsum[3 * HD + ch];
#pragma unroll
  for (int j = 0; j < 4; ++j) {
    int m = m0 + w * 16 + quad * 4 + j;
    float gi = acc0[j] + bsi;
    float gf = acc1[j] + bsf;
    float gg = acc2[j] + bsg;
    float go = acc3[j] + bso;
    int idx = m * HD + ch;
    float cn = sigm(gf) * cbuf[idx] + sigm(gi) * tanh_f(gg);
    cbuf[idx] = cn;
    float h = sigm(go) * tanh_f(cn);
    short h16 = f2b(h);
    xh_out[m * KC + ch] = f2b(h > 0.f ? h : 0.f);  // x-half: relu(h)
    xh_out[m * KC + HD + ch] = h16;                // h-half
    hs_out[idx] = h16;
  }
}

// ---------------- output projection over a CH-step chunk (LDS-free) ----------------
// grid (2, CH*BD/64). Wave: 16m x 64n (4 n-frags), K=1024.
__global__ __launch_bounds__(256) void out_proj(const short* __restrict__ hsC,
                                                const short* __restrict__ Wo,
                                                const float* __restrict__ bo,
                                                float* __restrict__ dout, int t0) {
  const int tid = threadIdx.x;
  const int w = tid >> 6, lan = tid & 15, quad = (tid & 63) >> 4;
  const int n0 = blockIdx.x * 64;
  const int m0 = blockIdx.y * 64;
  const short* ap = hsC + (size_t)(m0 + w * 16 + lan) * HD;
  f32x4 acc[4] = {};
#pragma unroll 2
  for (int k0 = 0; k0 < HD; k0 += 32) {
    const int ka = k0 + quad * 8;
    s16x8 a = *(const s16x8*)(ap + ka);
#pragma unroll
    for (int nf = 0; nf < 4; ++nf) {
      s16x8 b = *(const s16x8*)(Wo + (size_t)(n0 + nf * 16 + lan) * HD + ka);
      acc[nf] = __builtin_amdgcn_mfma_f32_16x16x32_bf16(a, b, acc[nf], 0, 0, 0);
    }
  }
#pragma unroll
  for (int nf = 0; nf < 4; ++nf) {
    int col = n0 + nf * 16 + lan;
    float bb = bo[col];
#pragma unroll
    for (int j = 0; j < 4; ++j) {
      int m = m0 + w * 16 + quad * 4 + j;  // chunk-local row = tc*BD + b
      int tc = m >> 8, b = m & 255;
      dout[(size_t)(b * TS + t0 + tc) * OD + col] = acc[nf][j] + bb;
    }
  }
}

extern "C" void kernel_launch(void* const* d_in, const int* in_sizes, int n_in,
                              void* d_out, int out_size, void* d_ws, size_t ws_size,
                              hipStream_t stream) {
  static const int exp_sizes[26] = {
      131072, 131072, 128, 524288, 1024, 524288, 1024, 131072, 1024,
      4194304, 4194304, 4096, 4096, 131072, 128, 524288, 1024, 1024, 1,
      524288, 1024, 1048576, 1024, 2048, 2, 1};
  if (n_in < 26) return;
  for (int i = 0; i < 26; ++i)
    if (in_sizes[i] != exp_sizes[i]) return;

  const float* enc_out = (const float*)d_in[0];
  const float* enc_hid = (const float*)d_in[1];
  const float* start_tok = (const float*)d_in[2];
  const float* l2h_w = (const float*)d_in[3];
  const float* l2h_b = (const float*)d_in[4];
  const float* l2h2_w = (const float*)d_in[5];
  const float* l2h2_b = (const float*)d_in[6];
  const float* emb_w = (const float*)d_in[7];
  const float* emb_b = (const float*)d_in[8];
  const float* Wih_f = (const float*)d_in[9];
  const float* Whh_f = (const float*)d_in[10];
  const float* bih = (const float*)d_in[11];
  const float* bhh = (const float*)d_in[12];
  const float* outw_f = (const float*)d_in[13];
  const float* outb = (const float*)d_in[14];
  const float* seq_w = (const float*)d_in[15];
  const float* seq_b = (const float*)d_in[16];
  const float* seq2_w = (const float*)d_in[17];
  const float* seq2_b = (const float*)d_in[18];
  const float* mass_w = (const float*)d_in[19];
  const float* mass_b = (const float*)d_in[20];
  const float* mass2_w = (const float*)d_in[21];
  const float* mass2_b = (const float*)d_in[22];
  const float* mass3_w = (const float*)d_in[23];
  const float* mass3_b = (const float*)d_in[24];

  // ---- workspace layout ----
  char* p = (char*)d_ws;
  float* c_buf = (float*)p;  p += (size_t)BD * HD * 4;        // 1 MB
  float* bsum = (float*)p;   p += (size_t)4 * HD * 4;         // 16 KB
  float* n1 = (float*)p;     p += (size_t)BD * HD * 4;        // 1 MB
  short* m1 = (short*)p;     p += (size_t)BD * HD * 2;        // 512 KB
  short* m2 = (short*)p;     p += (size_t)BD * HD * 2;        // 512 KB
  short* xrow = (short*)p;   p += (size_t)HD * 2;             // 2 KB
  short* xhA = (short*)p;    p += (size_t)BD * KC * 2;        // 1 MB
  short* xhB = (short*)p;    p += (size_t)BD * KC * 2;        // 1 MB
  short* Wcat = (short*)p;   p += (size_t)4 * HD * KC * 2;    // 16 MB
  short* outw = (short*)p;   p += (size_t)OD * HD * 2;        // 256 KB
  short* hsC = (short*)p;    // CH * BD * HD bf16
  size_t fixed_bytes = (size_t)(p - (char*)d_ws);
  const size_t step_bytes = (size_t)BD * HD * 2;
  int CH = 0;
  const int cands[7] = {25, 20, 10, 5, 4, 2, 1};
  for (int ci = 0; ci < 7; ++ci) {
    if (fixed_bytes + (size_t)cands[ci] * step_bytes <= ws_size) { CH = cands[ci]; break; }
  }
  if (CH == 0) return;

  float* dout = (float*)d_out;
  float* o_dec = dout;                       // [B][TS][OD]
  float* o_h = dout + (size_t)BD * TS * OD;  // [1][B][HD]
  float* o_c = o_h + (size_t)BD * HD;        // [1][B][HD]
  float* o_num = o_c + (size_t)BD * HD;      // [B][1]
  float* o_mass = o_num + BD;                // [B][2]

  // prep
  wcat_k<<<4 * HD * KC / 2048, 256, 0, stream>>>(Wih_f, Whh_f, Wcat);
  cvt8_k<<<OD * HD / 2048, 256, 0, stream>>>(outw_f, outw);
  bsum_k<<<16, 256, 0, stream>>>(bih, bhh, bsum);
  x0_k<<<4, 256, 0, stream>>>(start_tok, emb_w, emb_b, xrow);
  bcast_k<<<BD * HD / 256, 256, 0, stream>>>(xrow, xhA);

  // heads + initial state (grid (16 nb, 4 mb))
  dim3 fcg(16, 4);
  fc_mfma<LATD, false, false><<<fcg, 256, 0, stream>>>(enc_hid, l2h_w, l2h_b, xhA, KC, HD);
  fc_mfma<LATD, false, true><<<fcg, 256, 0, stream>>>(enc_hid, l2h2_w, l2h2_b, c_buf, 0, 0);
  fc_mfma<LATD, false, true><<<fcg, 256, 0, stream>>>(enc_out, seq_w, seq_b, n1, 0, 0);
  fc_mfma<LATD, false, false><<<fcg, 256, 0, stream>>>(enc_out, mass_w, mass_b, m1, HD, 0);
  fc_mfma<HD, true, false><<<fcg, 256, 0, stream>>>(m1, mass2_w, mass2_b, m2, HD, 0);
  num_k<<<64, 256, 0, stream>>>(n1, seq2_w, seq2_b, o_num);
  mass_k<<<64, 256, 0, stream>>>(m2, mass3_w, mass3_b, o_mass);

  // LSTM scan
  short* xs[2] = {xhA, xhB};
  for (int t = 0; t < TS; ++t) {
    int i = t & 1;
    lstm_step<<<dim3(64, 4), 256, 0, stream>>>(xs[i], c_buf, Wcat, bsum, xs[1 - i],
                                               hsC + (size_t)(t % CH) * BD * HD);
    if ((t + 1) % CH == 0) {
      out_proj<<<dim3(2, CH * BD / 64), 256, 0, stream>>>(hsC, outw, outb, o_dec, t + 1 - CH);
    }
  }
  // TS even -> final h in xhA's h-half, final c in c_buf
  copy_h_k<<<BD * HD / 256, 256, 0, stream>>>(xhA, o_h);
  copy_c_k<<<BD * HD / 256, 256, 0, stream>>>(c_buf, o_c);
}

// Round 6
// 2348.665 us; speedup vs baseline: 2.0028x; 1.9671x over previous
//
#include <hip/hip_runtime.h>

#define BD 256   // batch
#define HD 1024  // hidden
#define KC 2048  // concatenated K = [x | h]
#define LATD 512 // latent
#define OD 128   // output dim
#define TS 100   // seq_len (fixed by problem)

typedef __attribute__((ext_vector_type(8))) short s16x8;
typedef __attribute__((ext_vector_type(4))) float f32x4;

__device__ __forceinline__ float b2f(short s) {
  return __uint_as_float(((unsigned)(unsigned short)s) << 16);
}
__device__ __forceinline__ short f2b(float f) {
  unsigned u = __float_as_uint(f);
  u += 0x7fff + ((u >> 16) & 1);  // RNE
  return (short)(u >> 16);
}
__device__ __forceinline__ float sigm(float x) { return 1.f / (1.f + __expf(-x)); }
__device__ __forceinline__ float tanh_f(float x) { return 1.f - 2.f / (__expf(2.f * x) + 1.f); }

// ---------------- one-time prep kernels ----------------

// fp32 -> bf16, 8 elems/thread
__global__ __launch_bounds__(256) void cvt8_k(const float* __restrict__ in,
                                              short* __restrict__ out) {
  int i = (blockIdx.x * 256 + threadIdx.x) * 8;
  f32x4 a = *(const f32x4*)(in + i), b = *(const f32x4*)(in + i + 4);
  s16x8 o;
#pragma unroll
  for (int e = 0; e < 4; ++e) { o[e] = f2b(a[e]); o[4 + e] = f2b(b[e]); }
  *(s16x8*)(out + i) = o;
}

// Fragment-major weight repack:
// chunk index i = ((bn*64 + kit)*4 + quad)*16 + lan  (8 bf16 per chunk)
//   bn = g*64 + bx  (gate g, col-block bx -> rows g*1024 + bx*16 + lan)
//   k  = kit*32 + quad*8
// => a wave's B-frag (64 lanes x 16B) is contiguous 1 KB in memory.
__global__ __launch_bounds__(256) void wrep_k(const float* __restrict__ Wih,
                                              const float* __restrict__ Whh,
                                              short* __restrict__ Wt) {
  int i = blockIdx.x * 256 + threadIdx.x;  // chunk id, < 1048576
  int lan = i & 15, quad = (i >> 4) & 3, kit = (i >> 6) & 63, bn = i >> 12;
  int g = bn >> 6, bx = bn & 63;
  int n = g * HD + bx * 16 + lan;
  int k = kit * 32 + quad * 8;
  const float* src = (k < HD) ? (Wih + (size_t)n * HD + k)
                              : (Whh + (size_t)n * HD + (k - HD));
  f32x4 a = *(const f32x4*)src, b = *(const f32x4*)(src + 4);
  s16x8 o;
#pragma unroll
  for (int e = 0; e < 4; ++e) { o[e] = f2b(a[e]); o[4 + e] = f2b(b[e]); }
  *(s16x8*)(Wt + (size_t)i * 8) = o;
}

__global__ __launch_bounds__(256) void bsum_k(const float* __restrict__ bi,
                                              const float* __restrict__ bh,
                                              float* __restrict__ bs) {
  int i = blockIdx.x * 256 + threadIdx.x;
  bs[i] = bi[i] + bh[i];
}

// xrow = relu(start_token @ emb_fc_w^T + emb_fc_b), one row [HD], bf16
__global__ __launch_bounds__(256) void x0_k(const float* __restrict__ st,
                                            const float* __restrict__ W,
                                            const float* __restrict__ bias,
                                            short* __restrict__ xrow) {
  int j = blockIdx.x * 256 + threadIdx.x;
  float acc = 0.f;
  for (int k = 0; k < OD; ++k) acc += st[k] * W[j * OD + k];
  acc += bias[j];
  xrow[j] = f2b(acc > 0.f ? acc : 0.f);
}

__global__ __launch_bounds__(256) void bcast_k(const short* __restrict__ xrow,
                                               short* __restrict__ xh) {
  int i = blockIdx.x * 256 + threadIdx.x;  // over BD*HD
  int m = i >> 10, c = i & 1023;
  xh[m * KC + c] = xrow[c];
}

// ---------------- head GEMM: out = lrelu(A @ W^T + b), N=1024, M=256 ----------------
template <int K, bool IN_BF16, bool OUT_F32>
__global__ __launch_bounds__(256) void fc_mfma(const void* __restrict__ in_,
                                               const float* __restrict__ W,
                                               const float* __restrict__ bias,
                                               void* __restrict__ out_,
                                               int ostride, int ooff) {
  const int tid = threadIdx.x;
  const int w = tid >> 6, lan = tid & 15, quad = (tid & 63) >> 4;
  const int n0 = blockIdx.x * 64;
  const int m0 = blockIdx.y * 64;
  const int arow = m0 + w * 16 + lan;
  f32x4 acc[4] = {};
  for (int k0 = 0; k0 < K; k0 += 32) {
    const int ka = k0 + quad * 8;
    s16x8 af;
    if (IN_BF16) {
      af = *(const s16x8*)((const short*)in_ + arow * K + ka);
    } else {
      const float* ap = (const float*)in_ + arow * K + ka;
      f32x4 a0 = *(const f32x4*)ap, a1 = *(const f32x4*)(ap + 4);
#pragma unroll
      for (int e = 0; e < 4; ++e) { af[e] = f2b(a0[e]); af[4 + e] = f2b(a1[e]); }
    }
#pragma unroll
    for (int nf = 0; nf < 4; ++nf) {
      const float* bp = W + (n0 + nf * 16 + lan) * K + ka;
      f32x4 b0 = *(const f32x4*)bp, b1 = *(const f32x4*)(bp + 4);
      s16x8 bf;
#pragma unroll
      for (int e = 0; e < 4; ++e) { bf[e] = f2b(b0[e]); bf[4 + e] = f2b(b1[e]); }
      acc[nf] = __builtin_amdgcn_mfma_f32_16x16x32_bf16(af, bf, acc[nf], 0, 0, 0);
    }
  }
#pragma unroll
  for (int nf = 0; nf < 4; ++nf) {
    int col = n0 + nf * 16 + lan;
    float bb = bias[col];
#pragma unroll
    for (int j = 0; j < 4; ++j) {
      int m = m0 + w * 16 + quad * 4 + j;
      float v = acc[nf][j] + bb;
      v = v > 0.f ? v : 0.01f * v;
      if (OUT_F32)
        ((float*)out_)[m * 1024 + col] = v;
      else
        ((short*)out_)[m * ostride + ooff + col] = f2b(v);
    }
  }
}

__global__ __launch_bounds__(256) void num_k(const float* __restrict__ n1,
                                             const float* __restrict__ w2,
                                             const float* __restrict__ b2,
                                             float* __restrict__ out) {
  int l = threadIdx.x & 63, w = threadIdx.x >> 6;
  int m = blockIdx.x * 4 + w;
  const float* r = n1 + m * HD + l * 16;
  const float* wv = w2 + l * 16;
  float acc = 0.f;
#pragma unroll
  for (int c = 0; c < 4; ++c) {
    f32x4 a = *(const f32x4*)(r + c * 4), b = *(const f32x4*)(wv + c * 4);
#pragma unroll
    for (int e = 0; e < 4; ++e) acc += a[e] * b[e];
  }
  for (int off = 32; off; off >>= 1) acc += __shfl_down(acc, off);
  if (l == 0) {
    float v = acc + b2[0];
    out[m] = v > 0.f ? v : 0.f;
  }
}

__global__ __launch_bounds__(256) void mass_k(const short* __restrict__ m2,
                                              const float* __restrict__ w3,
                                              const float* __restrict__ b3,
                                              float* __restrict__ out) {
  int l = threadIdx.x & 63, w = threadIdx.x >> 6;
  int m = blockIdx.x * 4 + w;
  const short* r = m2 + m * HD + l * 16;
  s16x8 v0 = *(const s16x8*)r, v1 = *(const s16x8*)(r + 8);
  float z0 = 0.f, z1 = 0.f;
#pragma unroll
  for (int e = 0; e < 8; ++e) {
    float a = b2f(v0[e]), b = b2f(v1[e]);
    z0 += a * w3[l * 16 + e] + b * w3[l * 16 + 8 + e];
    z1 += a * w3[HD + l * 16 + e] + b * w3[HD + l * 16 + 8 + e];
  }
  for (int off = 32; off; off >>= 1) {
    z0 += __shfl_down(z0, off);
    z1 += __shfl_down(z1, off);
  }
  if (l == 0) {
    z0 += b3[0]; z1 += b3[1];
    float mx = fmaxf(z0, z1);
    float e0 = __expf(z0 - mx), e1 = __expf(z1 - mx);
    float s = e0 + e1;
    out[m * 2] = e0 / s;
    out[m * 2 + 1] = e1 / s;
  }
}

// ---------------- fused LSTM step v2 ----------------
// grid (64, 4), blockDim 1024 (16 waves). Block: 64 m-rows x 16 h-cols x 4 gates.
// Wave (mf = w&3, kq = w>>2): m-frag mf (16 rows), K-quarter kq (512).
// Per k-iter: 1 A-load (16 rows x 16B) + 4 contiguous-1KB B-loads + 4 MFMA.
// Register double-buffer keeps ~10 loads in flight. Partials reduced via LDS.
__global__ __launch_bounds__(1024) void lstm_step(
    const short* __restrict__ xh, float* __restrict__ cbuf,
    const short* __restrict__ Wt, const float* __restrict__ bsum,
    short* __restrict__ xh_out, short* __restrict__ hs_out,
    float* __restrict__ o_h, float* __restrict__ o_c, int last) {
  __shared__ float red[16 * 64 * 17];  // 69.6 KB: [wave][lane][17], +1 pad

  const int tid = threadIdx.x;
  const int w = tid >> 6, l = tid & 63;
  const int lan = l & 15, quad = l >> 4;
  const int mf = w & 3, kq = w >> 2;
  const int bx = blockIdx.x;          // 16 h-cols
  const int m0 = blockIdx.y * 64;     // 64 m-rows
  const int c0 = bx * 16;

  const short* ap = xh + (m0 + mf * 16 + lan) * KC + kq * 512 + quad * 8;
  // B frag base for gate g: chunk ((g*64+bx)*64 + kq*16)*4, +l chunks for lane
  const short* bp0 = Wt + ((size_t)(((0 * 64 + bx) * 64 + kq * 16) * 4) * 16 + (size_t)quad * 16 + lan) * 8;
  const short* bp1 = bp0 + (size_t)64 * 64 * 4 * 16 * 8;  // bn stride = 64*4*16*8 per kit... gate stride = 64 bn
  const short* bp2 = bp1 + (size_t)64 * 64 * 4 * 16 * 8;
  const short* bp3 = bp2 + (size_t)64 * 64 * 4 * 16 * 8;

  f32x4 acc0 = {}, acc1 = {}, acc2 = {}, acc3 = {};

  s16x8 a_c = *(const s16x8*)ap;
  s16x8 b_c0 = *(const s16x8*)bp0;
  s16x8 b_c1 = *(const s16x8*)bp1;
  s16x8 b_c2 = *(const s16x8*)bp2;
  s16x8 b_c3 = *(const s16x8*)bp3;
#pragma unroll 3
  for (int it = 0; it < 15; ++it) {
    s16x8 a_n = *(const s16x8*)(ap + (it + 1) * 32);
    s16x8 b_n0 = *(const s16x8*)(bp0 + (it + 1) * 512);
    s16x8 b_n1 = *(const s16x8*)(bp1 + (it + 1) * 512);
    s16x8 b_n2 = *(const s16x8*)(bp2 + (it + 1) * 512);
    s16x8 b_n3 = *(const s16x8*)(bp3 + (it + 1) * 512);
    acc0 = __builtin_amdgcn_mfma_f32_16x16x32_bf16(a_c, b_c0, acc0, 0, 0, 0);
    acc1 = __builtin_amdgcn_mfma_f32_16x16x32_bf16(a_c, b_c1, acc1, 0, 0, 0);
    acc2 = __builtin_amdgcn_mfma_f32_16x16x32_bf16(a_c, b_c2, acc2, 0, 0, 0);
    acc3 = __builtin_amdgcn_mfma_f32_16x16x32_bf16(a_c, b_c3, acc3, 0, 0, 0);
    a_c = a_n; b_c0 = b_n0; b_c1 = b_n1; b_c2 = b_n2; b_c3 = b_n3;
  }
  acc0 = __builtin_amdgcn_mfma_f32_16x16x32_bf16(a_c, b_c0, acc0, 0, 0, 0);
  acc1 = __builtin_amdgcn_mfma_f32_16x16x32_bf16(a_c, b_c1, acc1, 0, 0, 0);
  acc2 = __builtin_amdgcn_mfma_f32_16x16x32_bf16(a_c, b_c2, acc2, 0, 0, 0);
  acc3 = __builtin_amdgcn_mfma_f32_16x16x32_bf16(a_c, b_c3, acc3, 0, 0, 0);

  // stash partials
  float* slot = &red[(size_t)(w * 64 + l) * 17];
  *(f32x4*)(slot + 0) = acc0;
  *(f32x4*)(slot + 4) = acc1;
  *(f32x4*)(slot + 8) = acc2;
  *(f32x4*)(slot + 12) = acc3;
  __syncthreads();

  // epilogue: thread t -> cell (mloc = t>>4, hc = t&15)
  const int mloc = tid >> 4, hc = tid & 15;
  const int emf = mloc >> 4, eq = (mloc & 15) >> 2, ej = mloc & 3;
  const int elane = eq * 16 + hc;
  float g4[4];
#pragma unroll
  for (int g = 0; g < 4; ++g) {
    float s = 0.f;
#pragma unroll
    for (int k2 = 0; k2 < 4; ++k2)
      s += red[(size_t)((k2 * 4 + emf) * 64 + elane) * 17 + g * 4 + ej];
    g4[g] = s;
  }
  const int ch = c0 + hc;
  const int mg = m0 + mloc;
  float gi = g4[0] + bsum[ch];
  float gf = g4[1] + bsum[HD + ch];
  float gg = g4[2] + bsum[2 * HD + ch];
  float go = g4[3] + bsum[3 * HD + ch];
  int idx = mg * HD + ch;
  float cn = sigm(gf) * cbuf[idx] + sigm(gi) * tanh_f(gg);
  cbuf[idx] = cn;
  float h = sigm(go) * tanh_f(cn);
  short h16 = f2b(h);
  xh_out[mg * KC + ch] = f2b(h > 0.f ? h : 0.f);  // x-half: relu(h)
  xh_out[mg * KC + HD + ch] = h16;                // h-half
  hs_out[idx] = h16;
  if (last) {
    o_h[idx] = h;
    o_c[idx] = cn;
  }
}

// ---------------- output projection over a CH-step chunk ----------------
__global__ __launch_bounds__(256) void out_proj(const short* __restrict__ hsC,
                                                const short* __restrict__ Wo,
                                                const float* __restrict__ bo,
                                                float* __restrict__ dout, int t0) {
  const int tid = threadIdx.x;
  const int w = tid >> 6, lan = tid & 15, quad = (tid & 63) >> 4;
  const int n0 = blockIdx.x * 64;
  const int m0 = blockIdx.y * 64;
  const short* ap = hsC + (size_t)(m0 + w * 16 + lan) * HD;
  f32x4 acc[4] = {};
#pragma unroll 2
  for (int k0 = 0; k0 < HD; k0 += 32) {
    const int ka = k0 + quad * 8;
    s16x8 a = *(const s16x8*)(ap + ka);
#pragma unroll
    for (int nf = 0; nf < 4; ++nf) {
      s16x8 b = *(const s16x8*)(Wo + (size_t)(n0 + nf * 16 + lan) * HD + ka);
      acc[nf] = __builtin_amdgcn_mfma_f32_16x16x32_bf16(a, b, acc[nf], 0, 0, 0);
    }
  }
#pragma unroll
  for (int nf = 0; nf < 4; ++nf) {
    int col = n0 + nf * 16 + lan;
    float bb = bo[col];
#pragma unroll
    for (int j = 0; j < 4; ++j) {
      int m = m0 + w * 16 + quad * 4 + j;  // chunk-local row = tc*BD + b
      int tc = m >> 8, b = m & 255;
      dout[(size_t)(b * TS + t0 + tc) * OD + col] = acc[nf][j] + bb;
    }
  }
}

extern "C" void kernel_launch(void* const* d_in, const int* in_sizes, int n_in,
                              void* d_out, int out_size, void* d_ws, size_t ws_size,
                              hipStream_t stream) {
  static const int exp_sizes[26] = {
      131072, 131072, 128, 524288, 1024, 524288, 1024, 131072, 1024,
      4194304, 4194304, 4096, 4096, 131072, 128, 524288, 1024, 1024, 1,
      524288, 1024, 1048576, 1024, 2048, 2, 1};
  if (n_in < 26) return;
  for (int i = 0; i < 26; ++i)
    if (in_sizes[i] != exp_sizes[i]) return;

  const float* enc_out = (const float*)d_in[0];
  const float* enc_hid = (const float*)d_in[1];
  const float* start_tok = (const float*)d_in[2];
  const float* l2h_w = (const float*)d_in[3];
  const float* l2h_b = (const float*)d_in[4];
  const float* l2h2_w = (const float*)d_in[5];
  const float* l2h2_b = (const float*)d_in[6];
  const float* emb_w = (const float*)d_in[7];
  const float* emb_b = (const float*)d_in[8];
  const float* Wih_f = (const float*)d_in[9];
  const float* Whh_f = (const float*)d_in[10];
  const float* bih = (const float*)d_in[11];
  const float* bhh = (const float*)d_in[12];
  const float* outw_f = (const float*)d_in[13];
  const float* outb = (const float*)d_in[14];
  const float* seq_w = (const float*)d_in[15];
  const float* seq_b = (const float*)d_in[16];
  const float* seq2_w = (const float*)d_in[17];
  const float* seq2_b = (const float*)d_in[18];
  const float* mass_w = (const float*)d_in[19];
  const float* mass_b = (const float*)d_in[20];
  const float* mass2_w = (const float*)d_in[21];
  const float* mass2_b = (const float*)d_in[22];
  const float* mass3_w = (const float*)d_in[23];
  const float* mass3_b = (const float*)d_in[24];

  // ---- workspace layout ----
  char* p = (char*)d_ws;
  float* c_buf = (float*)p;  p += (size_t)BD * HD * 4;        // 1 MB
  float* bsum = (float*)p;   p += (size_t)4 * HD * 4;         // 16 KB
  float* n1 = (float*)p;     p += (size_t)BD * HD * 4;        // 1 MB
  short* m1 = (short*)p;     p += (size_t)BD * HD * 2;        // 512 KB
  short* m2 = (short*)p;     p += (size_t)BD * HD * 2;        // 512 KB
  short* xrow = (short*)p;   p += (size_t)HD * 2;             // 2 KB
  short* xhA = (short*)p;    p += (size_t)BD * KC * 2;        // 1 MB
  short* xhB = (short*)p;    p += (size_t)BD * KC * 2;        // 1 MB
  short* Wt = (short*)p;     p += (size_t)4 * HD * KC * 2;    // 16 MB
  short* outw = (short*)p;   p += (size_t)OD * HD * 2;        // 256 KB
  short* hsC = (short*)p;    // CH * BD * HD bf16
  size_t fixed_bytes = (size_t)(p - (char*)d_ws);
  const size_t step_bytes = (size_t)BD * HD * 2;
  int CH = 0;
  const int cands[7] = {25, 20, 10, 5, 4, 2, 1};
  for (int ci = 0; ci < 7; ++ci) {
    if (fixed_bytes + (size_t)cands[ci] * step_bytes <= ws_size) { CH = cands[ci]; break; }
  }
  if (CH == 0) return;

  float* dout = (float*)d_out;
  float* o_dec = dout;                       // [B][TS][OD]
  float* o_h = dout + (size_t)BD * TS * OD;  // [1][B][HD]
  float* o_c = o_h + (size_t)BD * HD;        // [1][B][HD]
  float* o_num = o_c + (size_t)BD * HD;      // [B][1]
  float* o_mass = o_num + BD;                // [B][2]

  // prep
  wrep_k<<<4096, 256, 0, stream>>>(Wih_f, Whh_f, Wt);
  cvt8_k<<<OD * HD / 2048, 256, 0, stream>>>(outw_f, outw);
  bsum_k<<<16, 256, 0, stream>>>(bih, bhh, bsum);
  x0_k<<<4, 256, 0, stream>>>(start_tok, emb_w, emb_b, xrow);
  bcast_k<<<BD * HD / 256, 256, 0, stream>>>(xrow, xhA);

  // heads + initial state
  dim3 fcg(16, 4);
  fc_mfma<LATD, false, false><<<fcg, 256, 0, stream>>>(enc_hid, l2h_w, l2h_b, xhA, KC, HD);
  fc_mfma<LATD, false, true><<<fcg, 256, 0, stream>>>(enc_hid, l2h2_w, l2h2_b, c_buf, 0, 0);
  fc_mfma<LATD, false, true><<<fcg, 256, 0, stream>>>(enc_out, seq_w, seq_b, n1, 0, 0);
  fc_mfma<LATD, false, false><<<fcg, 256, 0, stream>>>(enc_out, mass_w, mass_b, m1, HD, 0);
  fc_mfma<HD, true, false><<<fcg, 256, 0, stream>>>(m1, mass2_w, mass2_b, m2, HD, 0);
  num_k<<<64, 256, 0, stream>>>(n1, seq2_w, seq2_b, o_num);
  mass_k<<<64, 256, 0, stream>>>(m2, mass3_w, mass3_b, o_mass);

  // LSTM scan
  short* xs[2] = {xhA, xhB};
  for (int t = 0; t < TS; ++t) {
    int i = t & 1;
    lstm_step<<<dim3(64, 4), 1024, 0, stream>>>(
        xs[i], c_buf, Wt, bsum, xs[1 - i],
        hsC + (size_t)(t % CH) * BD * HD, o_h, o_c, (t == TS - 1) ? 1 : 0);
    if ((t + 1) % CH == 0) {
      out_proj<<<dim3(2, CH * BD / 64), 256, 0, stream>>>(hsC, outw, outb, o_dec, t + 1 - CH);
    }
  }
}

// Round 7
// 1835.328 us; speedup vs baseline: 2.5630x; 1.2797x over previous
//
#include <hip/hip_runtime.h>

#define BD 256   // batch
#define HD 1024  // hidden
#define KC 2048  // concatenated K = [x | h]
#define LATD 512 // latent
#define OD 128   // output dim
#define TS 100   // seq_len (fixed by problem)

typedef __attribute__((ext_vector_type(8))) short s16x8;
typedef __attribute__((ext_vector_type(4))) float f32x4;

__device__ __forceinline__ float b2f(short s) {
  return __uint_as_float(((unsigned)(unsigned short)s) << 16);
}
__device__ __forceinline__ short f2b(float f) {
  unsigned u = __float_as_uint(f);
  u += 0x7fff + ((u >> 16) & 1);  // RNE
  return (short)(u >> 16);
}
__device__ __forceinline__ float sigm(float x) { return 1.f / (1.f + __expf(-x)); }
__device__ __forceinline__ float tanh_f(float x) { return 1.f - 2.f / (__expf(2.f * x) + 1.f); }

// xh fragment-major chunk index: m -> (mt=m/16, r=m%16), k -> (kc=k/8, e=k%8)
// kq=kc/64, it=(kc/4)%16, q=kc%4; chunk = ((mt*4+kq)*16+it)*64 + q*16 + r
__device__ __forceinline__ size_t xhf_idx(int m, int k) {
  int kc = k >> 3;
  int kq = kc >> 6, it = (kc >> 2) & 15, q = kc & 3;
  int mt = m >> 4, r = m & 15;
  return ((((size_t)mt * 4 + kq) * 16 + it) * 64 + q * 16 + r) * 8 + (k & 7);
}

// ---------------- one-time prep kernels ----------------

__global__ __launch_bounds__(256) void cvt8_k(const float* __restrict__ in,
                                              short* __restrict__ out) {
  int i = (blockIdx.x * 256 + threadIdx.x) * 8;
  f32x4 a = *(const f32x4*)(in + i), b = *(const f32x4*)(in + i + 4);
  s16x8 o;
#pragma unroll
  for (int e = 0; e < 4; ++e) { o[e] = f2b(a[e]); o[4 + e] = f2b(b[e]); }
  *(s16x8*)(out + i) = o;
}

// Fragment-major weight repack (verified r6):
// chunk i = ((bn*64 + kit)*4 + quad)*16 + lan; bn = g*64+bx; k = kit*32+quad*8
__global__ __launch_bounds__(256) void wrep_k(const float* __restrict__ Wih,
                                              const float* __restrict__ Whh,
                                              short* __restrict__ Wt) {
  int i = blockIdx.x * 256 + threadIdx.x;  // chunk id, < 1048576
  int lan = i & 15, quad = (i >> 4) & 3, kit = (i >> 6) & 63, bn = i >> 12;
  int g = bn >> 6, bx = bn & 63;
  int n = g * HD + bx * 16 + lan;
  int k = kit * 32 + quad * 8;
  const float* src = (k < HD) ? (Wih + (size_t)n * HD + k)
                              : (Whh + (size_t)n * HD + (k - HD));
  f32x4 a = *(const f32x4*)src, b = *(const f32x4*)(src + 4);
  s16x8 o;
#pragma unroll
  for (int e = 0; e < 4; ++e) { o[e] = f2b(a[e]); o[4 + e] = f2b(b[e]); }
  *(s16x8*)(Wt + (size_t)i * 8) = o;
}

__global__ __launch_bounds__(256) void bsum_k(const float* __restrict__ bi,
                                              const float* __restrict__ bh,
                                              float* __restrict__ bs) {
  int i = blockIdx.x * 256 + threadIdx.x;
  bs[i] = bi[i] + bh[i];
}

__global__ __launch_bounds__(256) void x0_k(const float* __restrict__ st,
                                            const float* __restrict__ W,
                                            const float* __restrict__ bias,
                                            short* __restrict__ xrow) {
  int j = blockIdx.x * 256 + threadIdx.x;
  float acc = 0.f;
  for (int k = 0; k < OD; ++k) acc += st[k] * W[j * OD + k];
  acc += bias[j];
  xrow[j] = f2b(acc > 0.f ? acc : 0.f);
}

// x-half init: xhf[m][k] = xrow[k], k<1024
__global__ __launch_bounds__(256) void bcast_k(const short* __restrict__ xrow,
                                               short* __restrict__ xhf) {
  int i = blockIdx.x * 256 + threadIdx.x;  // over BD*HD
  int m = i >> 10, k = i & 1023;
  xhf[xhf_idx(m, k)] = xrow[k];
}

// ---------------- head GEMM: out = lrelu(A @ W^T + b), N=1024, M=256 ----------------
// MODE: 0 = fp32 flat [m*1024+col]; 1 = bf16 flat [m*os+oo+col]; 2 = bf16 xhf h-half
template <int K, bool IN_BF16, int MODE>
__global__ __launch_bounds__(256) void fc_mfma(const void* __restrict__ in_,
                                               const float* __restrict__ W,
                                               const float* __restrict__ bias,
                                               void* __restrict__ out_,
                                               int ostride, int ooff) {
  const int tid = threadIdx.x;
  const int w = tid >> 6, lan = tid & 15, quad = (tid & 63) >> 4;
  const int n0 = blockIdx.x * 64;
  const int m0 = blockIdx.y * 64;
  const int arow = m0 + w * 16 + lan;
  f32x4 acc[4] = {};
  for (int k0 = 0; k0 < K; k0 += 32) {
    const int ka = k0 + quad * 8;
    s16x8 af;
    if (IN_BF16) {
      af = *(const s16x8*)((const short*)in_ + arow * K + ka);
    } else {
      const float* ap = (const float*)in_ + arow * K + ka;
      f32x4 a0 = *(const f32x4*)ap, a1 = *(const f32x4*)(ap + 4);
#pragma unroll
      for (int e = 0; e < 4; ++e) { af[e] = f2b(a0[e]); af[4 + e] = f2b(a1[e]); }
    }
#pragma unroll
    for (int nf = 0; nf < 4; ++nf) {
      const float* bp = W + (n0 + nf * 16 + lan) * K + ka;
      f32x4 b0 = *(const f32x4*)bp, b1 = *(const f32x4*)(bp + 4);
      s16x8 bf;
#pragma unroll
      for (int e = 0; e < 4; ++e) { bf[e] = f2b(b0[e]); bf[4 + e] = f2b(b1[e]); }
      acc[nf] = __builtin_amdgcn_mfma_f32_16x16x32_bf16(af, bf, acc[nf], 0, 0, 0);
    }
  }
#pragma unroll
  for (int nf = 0; nf < 4; ++nf) {
    int col = n0 + nf * 16 + lan;
    float bb = bias[col];
#pragma unroll
    for (int j = 0; j < 4; ++j) {
      int m = m0 + w * 16 + quad * 4 + j;
      float v = acc[nf][j] + bb;
      v = v > 0.f ? v : 0.01f * v;
      if (MODE == 0)
        ((float*)out_)[m * 1024 + col] = v;
      else if (MODE == 1)
        ((short*)out_)[m * ostride + ooff + col] = f2b(v);
      else
        ((short*)out_)[xhf_idx(m, HD + col)] = f2b(v);
    }
  }
}

__global__ __launch_bounds__(256) void num_k(const float* __restrict__ n1,
                                             const float* __restrict__ w2,
                                             const float* __restrict__ b2,
                                             float* __restrict__ out) {
  int l = threadIdx.x & 63, w = threadIdx.x >> 6;
  int m = blockIdx.x * 4 + w;
  const float* r = n1 + m * HD + l * 16;
  const float* wv = w2 + l * 16;
  float acc = 0.f;
#pragma unroll
  for (int c = 0; c < 4; ++c) {
    f32x4 a = *(const f32x4*)(r + c * 4), b = *(const f32x4*)(wv + c * 4);
#pragma unroll
    for (int e = 0; e < 4; ++e) acc += a[e] * b[e];
  }
  for (int off = 32; off; off >>= 1) acc += __shfl_down(acc, off);
  if (l == 0) {
    float v = acc + b2[0];
    out[m] = v > 0.f ? v : 0.f;
  }
}

__global__ __launch_bounds__(256) void mass_k(const short* __restrict__ m2,
                                              const float* __restrict__ w3,
                                              const float* __restrict__ b3,
                                              float* __restrict__ out) {
  int l = threadIdx.x & 63, w = threadIdx.x >> 6;
  int m = blockIdx.x * 4 + w;
  const short* r = m2 + m * HD + l * 16;
  s16x8 v0 = *(const s16x8*)r, v1 = *(const s16x8*)(r + 8);
  float z0 = 0.f, z1 = 0.f;
#pragma unroll
  for (int e = 0; e < 8; ++e) {
    float a = b2f(v0[e]), b = b2f(v1[e]);
    z0 += a * w3[l * 16 + e] + b * w3[l * 16 + 8 + e];
    z1 += a * w3[HD + l * 16 + e] + b * w3[HD + l * 16 + 8 + e];
  }
  for (int off = 32; off; off >>= 1) {
    z0 += __shfl_down(z0, off);
    z1 += __shfl_down(z1, off);
  }
  if (l == 0) {
    z0 += b3[0]; z1 += b3[1];
    float mx = fmaxf(z0, z1);
    float e0 = __expf(z0 - mx), e1 = __expf(z1 - mx);
    float s = e0 + e1;
    out[m * 2] = e0 / s;
    out[m * 2 + 1] = e1 / s;
  }
}

// ---------------- fused LSTM step v3 ----------------
// grid (64, 4), blockDim 1024 (16 waves). Wave (mf=w&3, kq=w>>2).
// A and B both fragment-major: every wave-load is one contiguous 1 KB.
// 2-deep register pipeline: 10 loads in flight steady-state.
__global__ __launch_bounds__(1024) void lstm_step(
    const short* __restrict__ xhf, float* __restrict__ cbuf,
    const short* __restrict__ Wt, const float* __restrict__ bsum,
    short* __restrict__ xhf_out, short* __restrict__ hs_out,
    float* __restrict__ o_h, float* __restrict__ o_c, int last) {
  __shared__ float red[16 * 64 * 17];

  const int tid = threadIdx.x;
  const int w = tid >> 6, l = tid & 63;
  const int mf = w & 3, kq = w >> 2;
  const int bx = blockIdx.x;       // 16 h-cols
  const int by = blockIdx.y;       // 64 m-rows
  const int m0 = by * 64;
  const int c0 = bx * 16;

  // A: frag id = ((mt*4+kq)*16 + it), mt = by*4+mf; 512 shorts per frag
  const short* ap = xhf + (((size_t)(by * 4 + mf) * 4 + kq) * 16) * 512 + (size_t)l * 8;
  const int quad = l >> 4, lan = l & 15;
  const short* bp0 = Wt + ((size_t)(((0 * 64 + bx) * 64 + kq * 16) * 4) * 16 + (size_t)quad * 16 + lan) * 8;
  const short* bp1 = bp0 + (size_t)64 * 64 * 64 * 8;
  const short* bp2 = bp1 + (size_t)64 * 64 * 64 * 8;
  const short* bp3 = bp2 + (size_t)64 * 64 * 64 * 8;

  f32x4 acc0 = {}, acc1 = {}, acc2 = {}, acc3 = {};

  s16x8 aP = *(const s16x8*)ap;
  s16x8 b0P = *(const s16x8*)bp0;
  s16x8 b1P = *(const s16x8*)bp1;
  s16x8 b2P = *(const s16x8*)bp2;
  s16x8 b3P = *(const s16x8*)bp3;
  s16x8 aQ = *(const s16x8*)(ap + 512);
  s16x8 b0Q = *(const s16x8*)(bp0 + 512);
  s16x8 b1Q = *(const s16x8*)(bp1 + 512);
  s16x8 b2Q = *(const s16x8*)(bp2 + 512);
  s16x8 b3Q = *(const s16x8*)(bp3 + 512);
#pragma unroll
  for (int it = 0; it < 16; ++it) {
    if ((it & 1) == 0) {
      acc0 = __builtin_amdgcn_mfma_f32_16x16x32_bf16(aP, b0P, acc0, 0, 0, 0);
      acc1 = __builtin_amdgcn_mfma_f32_16x16x32_bf16(aP, b1P, acc1, 0, 0, 0);
      acc2 = __builtin_amdgcn_mfma_f32_16x16x32_bf16(aP, b2P, acc2, 0, 0, 0);
      acc3 = __builtin_amdgcn_mfma_f32_16x16x32_bf16(aP, b3P, acc3, 0, 0, 0);
      if (it + 2 < 16) {
        int o = (it + 2) * 512;
        aP = *(const s16x8*)(ap + o);
        b0P = *(const s16x8*)(bp0 + o);
        b1P = *(const s16x8*)(bp1 + o);
        b2P = *(const s16x8*)(bp2 + o);
        b3P = *(const s16x8*)(bp3 + o);
      }
    } else {
      acc0 = __builtin_amdgcn_mfma_f32_16x16x32_bf16(aQ, b0Q, acc0, 0, 0, 0);
      acc1 = __builtin_amdgcn_mfma_f32_16x16x32_bf16(aQ, b1Q, acc1, 0, 0, 0);
      acc2 = __builtin_amdgcn_mfma_f32_16x16x32_bf16(aQ, b2Q, acc2, 0, 0, 0);
      acc3 = __builtin_amdgcn_mfma_f32_16x16x32_bf16(aQ, b3Q, acc3, 0, 0, 0);
      if (it + 2 < 16) {
        int o = (it + 2) * 512;
        aQ = *(const s16x8*)(ap + o);
        b0Q = *(const s16x8*)(bp0 + o);
        b1Q = *(const s16x8*)(bp1 + o);
        b2Q = *(const s16x8*)(bp2 + o);
        b3Q = *(const s16x8*)(bp3 + o);
      }
    }
  }

  float* slot = &red[(size_t)(w * 64 + l) * 17];
  *(f32x4*)(slot + 0) = acc0;
  *(f32x4*)(slot + 4) = acc1;
  *(f32x4*)(slot + 8) = acc2;
  *(f32x4*)(slot + 12) = acc3;
  __syncthreads();

  // epilogue: thread t -> cell (mloc = t>>4, hc = t&15)   [verified r6]
  const int mloc = tid >> 4, hc = tid & 15;
  const int emf = mloc >> 4, eq = (mloc & 15) >> 2, ej = mloc & 3;
  const int elane = eq * 16 + hc;
  float g4[4];
#pragma unroll
  for (int g = 0; g < 4; ++g) {
    float s = 0.f;
#pragma unroll
    for (int k2 = 0; k2 < 4; ++k2)
      s += red[(size_t)((k2 * 4 + emf) * 64 + elane) * 17 + g * 4 + ej];
    g4[g] = s;
  }
  const int ch = c0 + hc;
  const int mg = m0 + mloc;
  float gi = g4[0] + bsum[ch];
  float gf = g4[1] + bsum[HD + ch];
  float gg = g4[2] + bsum[2 * HD + ch];
  float go = g4[3] + bsum[3 * HD + ch];
  int idx = mg * HD + ch;
  float cn = sigm(gf) * cbuf[idx] + sigm(gi) * tanh_f(gg);
  cbuf[idx] = cn;
  float h = sigm(go) * tanh_f(cn);
  short h16 = f2b(h);
  xhf_out[xhf_idx(mg, ch)] = f2b(h > 0.f ? h : 0.f);  // x-half: relu(h)
  xhf_out[xhf_idx(mg, HD + ch)] = h16;                // h-half
  hs_out[idx] = h16;
  if (last) {
    o_h[idx] = h;
    o_c[idx] = cn;
  }
}

// ---------------- output projection over a CH-step chunk ----------------
__global__ __launch_bounds__(256) void out_proj(const short* __restrict__ hsC,
                                                const short* __restrict__ Wo,
                                                const float* __restrict__ bo,
                                                float* __restrict__ dout, int t0) {
  const int tid = threadIdx.x;
  const int w = tid >> 6, lan = tid & 15, quad = (tid & 63) >> 4;
  const int n0 = blockIdx.x * 64;
  const int m0 = blockIdx.y * 64;
  const short* ap = hsC + (size_t)(m0 + w * 16 + lan) * HD;
  f32x4 acc[4] = {};
#pragma unroll 2
  for (int k0 = 0; k0 < HD; k0 += 32) {
    const int ka = k0 + quad * 8;
    s16x8 a = *(const s16x8*)(ap + ka);
#pragma unroll
    for (int nf = 0; nf < 4; ++nf) {
      s16x8 b = *(const s16x8*)(Wo + (size_t)(n0 + nf * 16 + lan) * HD + ka);
      acc[nf] = __builtin_amdgcn_mfma_f32_16x16x32_bf16(a, b, acc[nf], 0, 0, 0);
    }
  }
#pragma unroll
  for (int nf = 0; nf < 4; ++nf) {
    int col = n0 + nf * 16 + lan;
    float bb = bo[col];
#pragma unroll
    for (int j = 0; j < 4; ++j) {
      int m = m0 + w * 16 + quad * 4 + j;
      int tc = m >> 8, b = m & 255;
      dout[(size_t)(b * TS + t0 + tc) * OD + col] = acc[nf][j] + bb;
    }
  }
}

extern "C" void kernel_launch(void* const* d_in, const int* in_sizes, int n_in,
                              void* d_out, int out_size, void* d_ws, size_t ws_size,
                              hipStream_t stream) {
  static const int exp_sizes[26] = {
      131072, 131072, 128, 524288, 1024, 524288, 1024, 131072, 1024,
      4194304, 4194304, 4096, 4096, 131072, 128, 524288, 1024, 1024, 1,
      524288, 1024, 1048576, 1024, 2048, 2, 1};
  if (n_in < 26) return;
  for (int i = 0; i < 26; ++i)
    if (in_sizes[i] != exp_sizes[i]) return;

  const float* enc_out = (const float*)d_in[0];
  const float* enc_hid = (const float*)d_in[1];
  const float* start_tok = (const float*)d_in[2];
  const float* l2h_w = (const float*)d_in[3];
  const float* l2h_b = (const float*)d_in[4];
  const float* l2h2_w = (const float*)d_in[5];
  const float* l2h2_b = (const float*)d_in[6];
  const float* emb_w = (const float*)d_in[7];
  const float* emb_b = (const float*)d_in[8];
  const float* Wih_f = (const float*)d_in[9];
  const float* Whh_f = (const float*)d_in[10];
  const float* bih = (const float*)d_in[11];
  const float* bhh = (const float*)d_in[12];
  const float* outw_f = (const float*)d_in[13];
  const float* outb = (const float*)d_in[14];
  const float* seq_w = (const float*)d_in[15];
  const float* seq_b = (const float*)d_in[16];
  const float* seq2_w = (const float*)d_in[17];
  const float* seq2_b = (const float*)d_in[18];
  const float* mass_w = (const float*)d_in[19];
  const float* mass_b = (const float*)d_in[20];
  const float* mass2_w = (const float*)d_in[21];
  const float* mass2_b = (const float*)d_in[22];
  const float* mass3_w = (const float*)d_in[23];
  const float* mass3_b = (const float*)d_in[24];

  // ---- workspace layout ----
  char* p = (char*)d_ws;
  float* c_buf = (float*)p;  p += (size_t)BD * HD * 4;        // 1 MB
  float* bsum = (float*)p;   p += (size_t)4 * HD * 4;         // 16 KB
  float* n1 = (float*)p;     p += (size_t)BD * HD * 4;        // 1 MB
  short* m1 = (short*)p;     p += (size_t)BD * HD * 2;        // 512 KB
  short* m2 = (short*)p;     p += (size_t)BD * HD * 2;        // 512 KB
  short* xrow = (short*)p;   p += (size_t)HD * 2;             // 2 KB
  short* xhA = (short*)p;    p += (size_t)BD * KC * 2;        // 1 MB
  short* xhB = (short*)p;    p += (size_t)BD * KC * 2;        // 1 MB
  short* Wt = (short*)p;     p += (size_t)4 * HD * KC * 2;    // 16 MB
  short* outw = (short*)p;   p += (size_t)OD * HD * 2;        // 256 KB
  short* hsC = (short*)p;    // CH * BD * HD bf16
  size_t fixed_bytes = (size_t)(p - (char*)d_ws);
  const size_t step_bytes = (size_t)BD * HD * 2;
  int CH = 0;
  const int cands[7] = {25, 20, 10, 5, 4, 2, 1};
  for (int ci = 0; ci < 7; ++ci) {
    if (fixed_bytes + (size_t)cands[ci] * step_bytes <= ws_size) { CH = cands[ci]; break; }
  }
  if (CH == 0) return;

  float* dout = (float*)d_out;
  float* o_dec = dout;                       // [B][TS][OD]
  float* o_h = dout + (size_t)BD * TS * OD;  // [1][B][HD]
  float* o_c = o_h + (size_t)BD * HD;        // [1][B][HD]
  float* o_num = o_c + (size_t)BD * HD;      // [B][1]
  float* o_mass = o_num + BD;                // [B][2]

  // prep
  wrep_k<<<4096, 256, 0, stream>>>(Wih_f, Whh_f, Wt);
  cvt8_k<<<OD * HD / 2048, 256, 0, stream>>>(outw_f, outw);
  bsum_k<<<16, 256, 0, stream>>>(bih, bhh, bsum);
  x0_k<<<4, 256, 0, stream>>>(start_tok, emb_w, emb_b, xrow);
  bcast_k<<<BD * HD / 256, 256, 0, stream>>>(xrow, xhA);

  // heads + initial state
  dim3 fcg(16, 4);
  fc_mfma<LATD, false, 2><<<fcg, 256, 0, stream>>>(enc_hid, l2h_w, l2h_b, xhA, 0, 0);
  fc_mfma<LATD, false, 0><<<fcg, 256, 0, stream>>>(enc_hid, l2h2_w, l2h2_b, c_buf, 0, 0);
  fc_mfma<LATD, false, 0><<<fcg, 256, 0, stream>>>(enc_out, seq_w, seq_b, n1, 0, 0);
  fc_mfma<LATD, false, 1><<<fcg, 256, 0, stream>>>(enc_out, mass_w, mass_b, m1, HD, 0);
  fc_mfma<HD, true, 1><<<fcg, 256, 0, stream>>>(m1, mass2_w, mass2_b, m2, HD, 0);
  num_k<<<64, 256, 0, stream>>>(n1, seq2_w, seq2_b, o_num);
  mass_k<<<64, 256, 0, stream>>>(m2, mass3_w, mass3_b, o_mass);

  // LSTM scan
  short* xs[2] = {xhA, xhB};
  for (int t = 0; t < TS; ++t) {
    int i = t & 1;
    lstm_step<<<dim3(64, 4), 1024, 0, stream>>>(
        xs[i], c_buf, Wt, bsum, xs[1 - i],
        hsC + (size_t)(t % CH) * BD * HD, o_h, o_c, (t == TS - 1) ? 1 : 0);
    if ((t + 1) % CH == 0) {
      out_proj<<<dim3(2, CH * BD / 64), 256, 0, stream>>>(hsC, outw, outb, o_dec, t + 1 - CH);
    }
  }
}